// Round 1
// 220.171 us; speedup vs baseline: 1.2217x; 1.2217x over previous
//
#include <hip/hip_runtime.h>
#include <stdint.h>

// ---------------------------------------------------------------------------
// Social LSTM model, bf16 MFMA: A hi-only (RNE), B hi-only (RNE).
//   prep: packs B-frags (log2e/2*log2e folded) + dec bias; inits idx buf.
//   compact: builds dense list of VALID neighbour seq indices (counts mean
//         8/16 -> ~half the padded seqs are dead; reference masks them out).
//   enc:  LSTM(2->64), T=50. grid 2176 x 4 waves, 16 seqs/block; neighbour
//         blocks past the valid prefix EARLY-EXIT (~2x less neighbour work).
//         x gathered via idx; h written back to original seq slot.
//   dec:  LSTMCell(128->128), 30 steps. 256 blocks x 1024 thr. Unchanged.
// Accuracy ledger: absmax sat at 2^-10 from pure-fp32 R1 through B-hi-only
// R12; compaction computes identical math for all USED values (dead seqs
// never read by dec's masked max-pool).
// ---------------------------------------------------------------------------

#define T_SEQ 50
#define PRED_STEPS 30
#define NMAX 16

typedef float v2f __attribute__((ext_vector_type(2)));
typedef float v4f __attribute__((ext_vector_type(4)));
typedef short v8s __attribute__((ext_vector_type(8)));

#define L2E 1.44269504f
#define L2E2 2.88539008f

// ws layout (float offsets)
static constexpr size_t OFF_AEMB  = 0;          // 2048*64
static constexpr size_t OFF_NENC  = 131072;     // 32768*64
static constexpr size_t OFF_IDX   = 2228224;    // 32768 ints + 1 counter
static constexpr size_t OFF_PACKA = 2490368;    // 8192 floats (32 KB pack)
static constexpr size_t OFF_PACKN = 2498560;    // 8192 floats
static constexpr size_t OFF_WDP   = 2506752;    // 32768 floats (128 KB pack)
static constexpr size_t OFF_WDB   = 2539520;    // 512 floats fused dec bias

__device__ __forceinline__ float frcp(float x) { return __builtin_amdgcn_rcpf(x); }
#if __has_builtin(__builtin_amdgcn_exp2f)
__device__ __forceinline__ float fexp2(float x) { return __builtin_amdgcn_exp2f(x); }
#else
__device__ __forceinline__ float fexp2(float x) { return exp2f(x); }
#endif
__device__ __forceinline__ unsigned bf16rne(float f) {
  unsigned u = __float_as_uint(f);
  u += 0x7fff + ((u >> 16) & 1);
  return u >> 16;
}
__device__ __forceinline__ v4f mfma16(v8s a, v8s b, v4f c) {
  return __builtin_amdgcn_mfma_f32_16x16x32_bf16(a, b, c, 0, 0, 0);
}

// Shared-rcp LSTM cell. Gates PRE-SCALED: i,f,o by log2e; g by 2*log2e.
__device__ __forceinline__ float cell_update(float iv, float fv, float gv,
                                             float ov, float& cref) {
  float ef = fexp2(-fv);
  float ei = fexp2(-iv);
  float eg = fexp2(-gv);
  float t1 = (1.f + ei) * (1.f + eg);
  float rD = frcp((1.f + ef) * t1);
  float sf = t1 * rD;
  float u  = (1.f - eg) * ((1.f + ef) * rD);
  float cn = fmaf(sf, cref, u);
  cref = cn;
  float eo = fexp2(-ov);
  float ec = fexp2(fminf(-L2E2 * cn, 60.f));
  return (1.f - ec) * frcp((1.f + eo) * (1.f + ec));
}

// pack 8 consecutive scaled floats -> hi-only RNE bf16x8 (one uint4)
__device__ __forceinline__ uint4 pack8(const float* __restrict__ p, float gs) {
  float4 w0 = *(const float4*)p;
  float4 w1 = *(const float4*)(p + 4);
  uint4 o;
  o.x = bf16rne(w0.x * gs) | (bf16rne(w0.y * gs) << 16);
  o.y = bf16rne(w0.z * gs) | (bf16rne(w0.w * gs) << 16);
  o.z = bf16rne(w1.x * gs) | (bf16rne(w1.y * gs) << 16);
  o.w = bf16rne(w1.z * gs) | (bf16rne(w1.w * gs) << 16);
  return o;
}
__device__ __forceinline__ uint4 pack8sum(const float* __restrict__ pa,
                                          const float* __restrict__ pb, float gs) {
  float4 a0 = *(const float4*)pa, a1 = *(const float4*)(pa + 4);
  float4 b0 = *(const float4*)pb, b1 = *(const float4*)(pb + 4);
  uint4 o;
  o.x = bf16rne((a0.x + b0.x) * gs) | (bf16rne((a0.y + b0.y) * gs) << 16);
  o.y = bf16rne((a0.z + b0.z) * gs) | (bf16rne((a0.w + b0.w) * gs) << 16);
  o.z = bf16rne((a1.x + b1.x) * gs) | (bf16rne((a1.y + b1.y) * gs) << 16);
  o.w = bf16rne((a1.z + b1.z) * gs) | (bf16rne((a1.w + b1.w) * gs) << 16);
  return o;
}

// ---------------------------------------------------------------------------
// Merged prep, 48 blocks x 256. Also: idx buffer -> -1, counter -> 0.
// ---------------------------------------------------------------------------
__global__ void prep_kernel(const float* __restrict__ Whh_a, const float* __restrict__ Whh_n,
                            const float* __restrict__ Wih_d, const float* __restrict__ Whh_d,
                            const float* __restrict__ bih_d, const float* __restrict__ bhh_d,
                            uint4* __restrict__ packA, uint4* __restrict__ packN,
                            uint4* __restrict__ packD, float* __restrict__ bd,
                            int* __restrict__ idxb) {
  const int b = blockIdx.x;
  // init compaction structures (grid-stride over 48*256 = 12288 threads)
  {
    const int gi = b * 256 + threadIdx.x;
    for (int i = gi; i < 32768; i += 12288) idxb[i] = -1;
    if (gi == 0) idxb[32768] = 0;  // atomic counter / Nv
  }
  if (b < 16) {
    const int which = b >> 3;
    const float* Whh = which ? Whh_n : Whh_a;
    uint4* dst = which ? packN : packA;
    const int idx = (b & 7) * 256 + threadIdx.x;   // 0..2047
    const int lane = idx & 63, c = idx >> 6;       // c 0..31
    const int kh = c & 1, g = (c >> 1) & 3, w = c >> 3;
    const float gs = (g == 2) ? L2E2 : L2E;
    const int row = g * 64 + 16 * w + (lane & 15);
    const int kb = kh * 32 + (lane >> 4) * 8;
    dst[c * 64 + lane] = pack8(Whh + row * 64 + kb, gs);
  } else {
    const int idx = (b - 16) * 256 + threadIdx.x;  // 0..8191
    const int lane = idx & 63, c = idx >> 6;       // c 0..127
    const int kh = c & 3, i = (c >> 2) & 1, wv = c >> 3;
    const int g = wv & 3, q = wv >> 2;
    const float gs = (g == 2) ? L2E2 : L2E;
    const int ju = q * 32 + i * 16 + (lane & 15);
    const int row = g * 128 + ju;
    const int kb = kh * 32 + (lane >> 4) * 8;
    packD[c * 64 + lane] = pack8sum(Wih_d + row * 128 + kb, Whh_d + row * 128 + kb, gs);
    if (b < 18) {
      int iB = (b - 16) * 256 + threadIdx.x;       // 0..511
      float s = ((iB >> 7) == 2) ? L2E2 : L2E;
      bd[iB] = (bih_d[iB] + bhh_d[iB]) * s;
    }
  }
}

// ---------------------------------------------------------------------------
// Compaction: dense prefix of valid neighbour seq indices. 8 blocks x 256.
// Order within the prefix is arbitrary (atomic) -- results are written back
// to original seq slots, so the final output is deterministic.
// ---------------------------------------------------------------------------
__global__ void compact_kernel(const int* __restrict__ cnts, int* __restrict__ idxb) {
  const int b = blockIdx.x * 256 + threadIdx.x;
  if (b >= 2048) return;
  int cnt = cnts[b];
  cnt = cnt < 0 ? 0 : (cnt > NMAX ? NMAX : cnt);
  if (cnt == 0) return;
  int pos = atomicAdd(idxb + 32768, cnt);
  for (int j = 0; j < cnt; ++j) idxb[pos + j] = b * NMAX + j;
}

// ---------------------------------------------------------------------------
// Encoder. Blocks [0,2048) neighbour (compacted; early-exit past Nv),
// [2048,2176) agent; 256 thr = 4 waves. Ping-pong h planes (halfwords,
// HI-ONLY): buf b at base b*1152; row stride 72. 8 MFMA/step.
// ---------------------------------------------------------------------------
__global__ __launch_bounds__(256, 4) void enc_mfma_kernel(
    const float* __restrict__ xA, const float* __restrict__ xN,
    const v8s* __restrict__ packA, const v8s* __restrict__ packN,
    const float* __restrict__ Wih_a, const float* __restrict__ bih_a, const float* __restrict__ bhh_a,
    const float* __restrict__ Wih_n, const float* __restrict__ bih_n, const float* __restrict__ bhh_n,
    const int* __restrict__ idxb,
    float* __restrict__ outA, float* __restrict__ outN) {
  __shared__ unsigned short hph[2304];  // 2 ping-pong hi-planes
  __shared__ float xst[1600];
  __shared__ int sidx[16];
  const int tid = threadIdx.x, lane = tid & 63, wv = tid >> 6;
  const int nb = blockIdx.x;
  const bool isA = nb >= 2048;
  const int s0 = (isA ? nb - 2048 : nb) * 16;

  // dead neighbour blocks: everything past the compacted valid prefix
  if (!isA && s0 >= idxb[32768]) return;

  const float* xsrc = isA ? xA : xN;
  const v8s* pk = isA ? packA : packN;
  const float* Wih = isA ? Wih_a : Wih_n;
  const float* bih = isA ? bih_a : bih_n;
  const float* bhh = isA ? bhh_a : bhh_n;
  float* outp = isA ? outA : outN;

  // coalesced B-frag load (hi-only): chunk = wv*8+g*2+kh
  v8s B[4][2];
#pragma unroll
  for (int g = 0; g < 4; ++g)
#pragma unroll
    for (int kh = 0; kh < 2; ++kh)
      B[g][kh] = pk[(wv * 8 + g * 2 + kh) * 64 + lane];

  const int jc = lane & 15, qc = lane >> 4;  // C roles: unit col, seq quad
  float wi0[4], wi1[4], bs[4];
#pragma unroll
  for (int g = 0; g < 4; ++g) {
    const float gs = (g == 2) ? L2E2 : L2E;
    int n = g * 64 + 16 * wv + jc;
    wi0[g] = Wih[n * 2 + 0] * gs;
    wi1[g] = Wih[n * 2 + 1] * gs;
    bs[g] = (bih[n] + bhh[n]) * gs;
  }

  // seq index table + zero buf0, then gather-stage x (16 seqs x 100 floats)
  {
    if (tid < 16) sidx[tid] = isA ? (s0 + tid) : idxb[s0 + tid];
    for (int i = tid; i < 576; i += 256) ((unsigned*)hph)[i] = 0;
    __syncthreads();  // sidx visible
    for (int i = tid; i < 400; i += 256) {
      int slot = i / 25, j = i - slot * 25;  // 25 float4 per seq
      int sq = sidx[slot];
      const float4* xb = (const float4*)(xsrc + (size_t)(sq < 0 ? 0 : sq) * 100);
      ((float4*)xst)[i] = xb[j];
    }
  }
  __syncthreads();

  const int ms = lane & 15, ks = lane >> 4;  // A roles: seq row, k-quad
  float cst[4] = {0.f, 0.f, 0.f, 0.f};
  float h[4];

  auto enc_step = [&](int t, int rb, int wb) {
    // acc init: exact fp32 input projection + bias (scaled)
    v4f a4[4];
#pragma unroll
    for (int r = 0; r < 4; ++r) {
      v2f xv = *(const __shared__ v2f*)&xst[(qc * 4 + r) * 100 + 2 * t];
#pragma unroll
      for (int g = 0; g < 4; ++g)
        a4[g][r] = fmaf(wi1[g], xv.y, fmaf(wi0[g], xv.x, bs[g]));
    }

    // h @ Whh^T, A hi-only: 8 MFMA
#pragma unroll
    for (int kh = 0; kh < 2; ++kh) {
      v8s Ahi = *(const __shared__ v8s*)&hph[rb + ms * 72 + kh * 32 + ks * 8];
#pragma unroll
      for (int g = 0; g < 4; ++g)
        a4[g] = mfma16(Ahi, B[g][kh], a4[g]);
    }

    // pointwise + RNE bf16 h-store into the OTHER buffer
#pragma unroll
    for (int r = 0; r < 4; ++r) {
      h[r] = cell_update(a4[0][r], a4[1][r], a4[2][r], a4[3][r], cst[r]);
      hph[wb + (qc * 4 + r) * 72 + 16 * wv + jc] =
          (unsigned short)bf16rne(h[r]);
    }
    __syncthreads();
  };

  for (int t2 = 0; t2 < T_SEQ; t2 += 2) {
    enc_step(t2 + 0, 0, 1152);
    enc_step(t2 + 1, 1152, 0);
  }

#pragma unroll
  for (int r = 0; r < 4; ++r) {
    int sq = sidx[qc * 4 + r];
    if (sq >= 0)
      outp[(size_t)sq * 64 + 16 * wv + jc] = h[r];
  }
}

// ---------------------------------------------------------------------------
// Decoder v7. 256 blocks x 1024 thr (16 waves), 8 seqs/block.
// Wave wv: gate g = wv&3, unit-quarter q = wv>>2 -> 2 col-tiles of 16
// units; A hi-only -> 8 MFMA/step. Preds in LDS, one store.
// ---------------------------------------------------------------------------
__global__ __launch_bounds__(1024, 4) void dec_mfma_kernel(
    const v8s* __restrict__ pkd, const float* __restrict__ bd,
    const float* __restrict__ aemb, const float* __restrict__ nenc,
    const int* __restrict__ cnts, const float* __restrict__ Wpos,
    const float* __restrict__ bpos, float* __restrict__ out) {
  __shared__ unsigned short hph[2176];   // hi-only, row stride 136
  __shared__ float gbuf[4][8][132];
  __shared__ float ppart[16][2];
  __shared__ float pbuf[480];
  const int tid = threadIdx.x, lane = tid & 63, wv = tid >> 6;  // wv 0..15
  const int jc = lane & 15, qc = lane >> 4;
  const int g = wv & 3, q = wv >> 2;
  const int s0 = blockIdx.x * 8;

  // coalesced B-frag load: chunk = wv*8+i*4+kh
  v8s B[2][4];
  float bs[2];
#pragma unroll
  for (int i = 0; i < 2; ++i) {
#pragma unroll
    for (int kh = 0; kh < 4; ++kh)
      B[i][kh] = pkd[(wv * 8 + i * 4 + kh) * 64 + lane];
    bs[i] = bd[g * 128 + q * 32 + i * 16 + jc];
  }

  // cell-phase constants: seq sq = wv>>1, unit cu = (wv&1)*64 + lane
  const int cu = (wv & 1) * 64 + lane;
  const int sq = wv >> 1;
  const float wp0 = Wpos[cu], wp1 = Wpos[128 + cu];
  const float bp0 = bpos[0], bp1 = bpos[1];

  // stage h0 rows 0..7 (fused hmax, batched loads) + zero rows 8..15
  for (int i = tid; i < 2048; i += 1024) {
    int row = i >> 7, unit = i & 127;
    unsigned hiw = 0;
    if (row < 8) {
      float v;
      if (unit < 64) {
        v = aemb[(size_t)(s0 + row) * 64 + unit];
      } else {
        int cnt = cnts[s0 + row];
        float m = -1e30f;
#pragma unroll
        for (int n = 0; n < NMAX; ++n) {
          float val = nenc[((size_t)((s0 + row) * NMAX + n)) * 64 + (unit - 64)];
          m = (n < cnt) ? fmaxf(m, val) : m;
        }
        v = (cnt > 0) ? m : 0.f;
      }
      hiw = bf16rne(v);
    }
    hph[row * 136 + unit] = (unsigned short)hiw;
  }
  float cst = 0.f;
  __syncthreads();

  for (int t = 0; t < PRED_STEPS; ++t) {
    v4f acc[2];
#pragma unroll
    for (int i = 0; i < 2; ++i)
      acc[i] = (v4f){bs[i], bs[i], bs[i], bs[i]};
#pragma unroll
    for (int kh = 0; kh < 4; ++kh) {
      v8s Ahi = *(const __shared__ v8s*)&hph[jc * 136 + kh * 32 + qc * 8];
#pragma unroll
      for (int i = 0; i < 2; ++i)
        acc[i] = mfma16(Ahi, B[i][kh], acc[i]);
    }

    // publish gates (rows 0..7 -> lanes qc<2)
    if (qc < 2) {
#pragma unroll
      for (int i = 0; i < 2; ++i)
#pragma unroll
        for (int r = 0; r < 4; ++r)
          gbuf[g][qc * 4 + r][q * 32 + i * 16 + jc] = acc[i][r];
    }
    __syncthreads();  // barrier1: gates visible, A-reads complete

    // cell phase: 1 cell per thread (seq sq, unit cu)
    float gI = gbuf[0][sq][cu];
    float gF = gbuf[1][sq][cu];
    float gG = gbuf[2][sq][cu];
    float gO = gbuf[3][sq][cu];
    float h = cell_update(gI, gF, gG, gO, cst);

    hph[sq * 136 + cu] = (unsigned short)bf16rne(h);

    // pred partials: wave covers 64 of 128 units of seq sq
    float p0 = h * wp0;
    float p1 = h * wp1;
#pragma unroll
    for (int off = 32; off > 0; off >>= 1) {
      p0 += __shfl_xor(p0, off, 64);
      p1 += __shfl_xor(p1, off, 64);
    }
    if (lane == 0) { ppart[wv][0] = p0; ppart[wv][1] = p1; }
    __syncthreads();  // barrier2: h plane + ppart visible

    if (tid < 16) {
      int s = tid >> 1, cc = tid & 1;
      pbuf[s * 60 + t * 2 + cc] =
          ppart[2 * s][cc] + ppart[2 * s + 1][cc] + (cc ? bp1 : bp0);
    }
  }
  __syncthreads();
  if (tid < 480) out[(size_t)s0 * 60 + tid] = pbuf[tid];
}

extern "C" void kernel_launch(void* const* d_in, const int* in_sizes, int n_in,
                              void* d_out, int out_size, void* d_ws, size_t ws_size,
                              hipStream_t stream) {
  (void)in_sizes; (void)n_in; (void)out_size; (void)ws_size;
  const float* xA    = (const float*)d_in[0];
  const float* xN    = (const float*)d_in[1];
  const int*   cnts  = (const int*)d_in[2];
  const float* Wih_a = (const float*)d_in[3];
  const float* Whh_a = (const float*)d_in[4];
  const float* bih_a = (const float*)d_in[5];
  const float* bhh_a = (const float*)d_in[6];
  const float* Wih_n = (const float*)d_in[7];
  const float* Whh_n = (const float*)d_in[8];
  const float* bih_n = (const float*)d_in[9];
  const float* bhh_n = (const float*)d_in[10];
  const float* Wih_d = (const float*)d_in[11];
  const float* Whh_d = (const float*)d_in[12];
  const float* bih_d = (const float*)d_in[13];
  const float* bhh_d = (const float*)d_in[14];
  const float* Wpos  = (const float*)d_in[15];
  const float* bpos  = (const float*)d_in[16];
  float* out = (float*)d_out;
  float* wsf = (float*)d_ws;
  int* idxb = (int*)(wsf + OFF_IDX);

  prep_kernel<<<48, 256, 0, stream>>>(Whh_a, Whh_n, Wih_d, Whh_d, bih_d, bhh_d,
                                      (uint4*)(wsf + OFF_PACKA),
                                      (uint4*)(wsf + OFF_PACKN),
                                      (uint4*)(wsf + OFF_WDP), wsf + OFF_WDB,
                                      idxb);
  compact_kernel<<<8, 256, 0, stream>>>(cnts, idxb);
  enc_mfma_kernel<<<2176, 256, 0, stream>>>(
      xA, xN,
      (const v8s*)(wsf + OFF_PACKA), (const v8s*)(wsf + OFF_PACKN),
      Wih_a, bih_a, bhh_a, Wih_n, bih_n, bhh_n, idxb,
      wsf + OFF_AEMB, wsf + OFF_NENC);
  dec_mfma_kernel<<<256, 1024, 0, stream>>>(
      (const v8s*)(wsf + OFF_WDP), wsf + OFF_WDB,
      wsf + OFF_AEMB, wsf + OFF_NENC, cnts,
      Wpos, bpos, out);
}